// Round 1
// baseline (573.481 us; speedup 1.0000x reference)
//
#include <hip/hip_runtime.h>
#include <hip/hip_bf16.h>
#include <math.h>

#define NB 8
#define INCH 512
#define OUTCH 256
#define SP 4096          // 64*64 spatial
#define LAT 512
#define NTAP 9
#define MDIM (NTAP*OUTCH)   // 2304

#define INV_SQRT_LAT 0.044194173824159216f   // 1/sqrt(512)
#define WSCALE 0.014731391274719738f         // 1/sqrt(512*9)

typedef __bf16 bf16x8 __attribute__((ext_vector_type(8)));
typedef float  f32x4  __attribute__((ext_vector_type(4)));

__device__ __forceinline__ unsigned short f2bf(float f) {
  unsigned u = __float_as_uint(f);
  u += 0x7fffu + ((u >> 16) & 1u);       // round-to-nearest-even
  return (unsigned short)(u >> 16);
}

// ---------------- stage 0a: style[b,i] = w[b,:] @ aff[i,:] / sqrt(512) + bias[i]
__global__ void style_k(const float* __restrict__ w, const float* __restrict__ aff,
                        const float* __restrict__ bias, float* __restrict__ style) {
  int gid = blockIdx.x * 256 + threadIdx.x;       // 4096
  int b = gid >> 9, i = gid & 511;
  const float4* wv = (const float4*)(w + (size_t)b * LAT);
  const float4* av = (const float4*)(aff + (size_t)i * LAT);
  float s = 0.f;
#pragma unroll 4
  for (int l = 0; l < LAT / 4; ++l) {
    float4 a = av[l], ww = wv[l];
    s += a.x * ww.x + a.y * ww.y + a.z * ww.z + a.w * ww.w;
  }
  style[gid] = s * INV_SQRT_LAT + bias[i];
}

// ---------------- stage 0b: S[o,i] = scale^2 * sum_cd base^2 ; w9[tap][o][i] = bf16(scale*base)
__global__ void wprep_k(const float* __restrict__ cw, float* __restrict__ S,
                        unsigned short* __restrict__ w9) {
  int gid = blockIdx.x * 256 + threadIdx.x;       // 131072 = 256*512
  int o = gid >> 9, i = gid & 511;
  const float* p = cw + (size_t)gid * 9;          // gid == o*512+i, layout (o,i,3,3)
  float ss = 0.f, v[9];
#pragma unroll
  for (int t = 0; t < 9; ++t) { v[t] = p[t]; ss += v[t] * v[t]; }
  S[gid] = ss * (WSCALE * WSCALE);
#pragma unroll
  for (int t = 0; t < 9; ++t)
    w9[((size_t)(t * OUTCH + o)) * INCH + i] = f2bf(v[t] * WSCALE);
}

// ---------------- stage 0c: demod[b,o] = rsqrt(sum_i style^2 * S + 1e-8)
__global__ void demod_k(const float* __restrict__ style, const float* __restrict__ S,
                        float* __restrict__ dmod) {
  int gid = blockIdx.x * 256 + threadIdx.x;       // 2048
  int b = gid >> 8, o = gid & 255;
  const float4* sv = (const float4*)(style + (size_t)b * INCH);
  const float4* Sv = (const float4*)(S + (size_t)o * INCH);
  float acc = 0.f;
#pragma unroll 4
  for (int l = 0; l < INCH / 4; ++l) {
    float4 st = sv[l], s2 = Sv[l];
    acc += st.x * st.x * s2.x + st.y * st.y * s2.y + st.z * st.z * s2.z + st.w * st.w * s2.w;
  }
  dmod[gid] = 1.0f / sqrtf(acc + 1e-8f);
}

// ---------------- stage 0d: xmt[b][s][i] = bf16(x[b][i][s] * style[b][i])   (transpose)
__global__ void modx_k(const float* __restrict__ x, const float* __restrict__ style,
                       unsigned short* __restrict__ xmt) {
  __shared__ float tile[32][33];
  int b = blockIdx.z;
  int s0 = blockIdx.x * 32;
  int i0 = blockIdx.y * 32;
  int c = threadIdx.x & 31, r = threadIdx.x >> 5;   // 32 x 8
#pragma unroll
  for (int p = 0; p < 4; ++p) {
    int ii = r + p * 8;
    tile[ii][c] = x[((size_t)(b * INCH + i0 + ii)) * SP + s0 + c] * style[b * INCH + i0 + ii];
  }
  __syncthreads();
#pragma unroll
  for (int p = 0; p < 4; ++p) {
    int ss = r + p * 8;
    xmt[((size_t)(b * SP + s0 + ss)) * INCH + i0 + c] = f2bf(tile[c][ss]);
  }
}

// ---------------- stage 1: T[m, n] = sum_k A[m,k] * B[n,k]   (m97-style bf16 MFMA GEMM, B^T input)
// M=2304 N=4096 K=512, tile 128x128, BK=64, 4 waves, global_load_lds w=16, XOR-16B-chunk swizzle
__global__ __launch_bounds__(256, 2)
void gemm_k(const unsigned short* __restrict__ A,   // MDIM x INCH
            const unsigned short* __restrict__ Bm,  // SP x INCH (per-sample base)
            float* __restrict__ C) {                // MDIM x SP
  __shared__ __align__(16) unsigned short As[128 * 64];
  __shared__ __align__(16) unsigned short Bs[128 * 64];
  Bm += (size_t)blockIdx.z * SP * INCH;
  C  += (size_t)blockIdx.z * MDIM * SP;
  const int tid  = threadIdx.x;
  const int lane = tid & 63;
  const int wave = tid >> 6;
  const int m0 = blockIdx.y * 128;
  const int n0 = blockIdx.x * 128;
  const int wm = (wave >> 1) * 64;
  const int wn = (wave & 1) * 64;
  const int lrow   = lane >> 3;             // 0..7
  const int gchunk = (lane & 7) ^ lrow;     // swizzled 16B chunk in global row

  f32x4 acc[4][4];
#pragma unroll
  for (int i = 0; i < 4; ++i)
#pragma unroll
    for (int j = 0; j < 4; ++j) acc[i][j] = (f32x4){0.f, 0.f, 0.f, 0.f};

  const int r16  = lane & 15;
  const int quad = lane >> 4;

  for (int k0 = 0; k0 < INCH; k0 += 64) {
#pragma unroll
    for (int it = 0; it < 4; ++it) {
      int rbase = it * 32 + wave * 8;
      const unsigned short* ga = A  + (size_t)(m0 + rbase + lrow) * INCH + k0 + gchunk * 8;
      const unsigned short* gb = Bm + (size_t)(n0 + rbase + lrow) * INCH + k0 + gchunk * 8;
      __builtin_amdgcn_global_load_lds((const __attribute__((address_space(1))) void*)ga,
                                       (__attribute__((address_space(3))) void*)&As[rbase * 64],
                                       16, 0, 0);
      __builtin_amdgcn_global_load_lds((const __attribute__((address_space(1))) void*)gb,
                                       (__attribute__((address_space(3))) void*)&Bs[rbase * 64],
                                       16, 0, 0);
    }
    __syncthreads();
#pragma unroll
    for (int kk = 0; kk < 2; ++kk) {
      bf16x8 af[4], bfr[4];
#pragma unroll
      for (int i = 0; i < 4; ++i) {
        int rowa = wm + i * 16 + r16;
        int cha  = (kk * 4 + quad) ^ (rowa & 7);
        af[i] = *(const bf16x8*)&As[rowa * 64 + cha * 8];
        int rowb = wn + i * 16 + r16;
        int chb  = (kk * 4 + quad) ^ (rowb & 7);
        bfr[i] = *(const bf16x8*)&Bs[rowb * 64 + chb * 8];
      }
#pragma unroll
      for (int i = 0; i < 4; ++i)
#pragma unroll
        for (int j = 0; j < 4; ++j)
          acc[i][j] = __builtin_amdgcn_mfma_f32_16x16x32_bf16(af[i], bfr[j], acc[i][j], 0, 0, 0);
    }
    __syncthreads();
  }
  // epilogue: C/D layout col=lane&15, row=quad*4+reg  [m89-verified]
#pragma unroll
  for (int i = 0; i < 4; ++i)
#pragma unroll
    for (int j = 0; j < 4; ++j)
#pragma unroll
      for (int r = 0; r < 4; ++r) {
        int mrow = m0 + wm + i * 16 + quad * 4 + r;
        int ncol = n0 + wn + j * 16 + r16;
        C[(size_t)mrow * SP + ncol] = acc[i][j][r];
      }
}

// ---------------- stage 2: parity-combine taps + 4x4 blur + demod
// res[2Y+py,2X+px] = demod/16 * sum_{c,d} sum_{j,k in -1..1} kvz[py+4-2jj-c]*kvz[px+4-2kk-d]*T[c*3+d][Y+j,X+k]
__global__ void combine_k(const float* __restrict__ T, const float* __restrict__ dm,
                          float* __restrict__ out) {
  __shared__ float Tl[9 * 18 * 18];
  T   += (size_t)blockIdx.z * MDIM * SP;
  dm  += (size_t)blockIdx.z * OUTCH;
  out += (size_t)blockIdx.z * OUTCH * 128 * 128;
  const int o = blockIdx.y;
  const int Ty = blockIdx.x >> 2, Tx = blockIdx.x & 3;
  const int tid = threadIdx.x;
  for (int idx = tid; idx < 9 * 18 * 18; idx += 256) {
    int tap = idx / 324;
    int rem = idx - tap * 324;
    int yy = rem / 18;
    int xx = rem - yy * 18;
    int Yg = Ty * 16 - 1 + yy;
    int Xg = Tx * 16 - 1 + xx;
    float v = 0.f;
    if ((unsigned)Yg < 64u && (unsigned)Xg < 64u)
      v = T[((size_t)(tap * OUTCH + o)) * SP + Yg * 64 + Xg];
    Tl[idx] = v;
  }
  __syncthreads();
  const int Yl = tid >> 4, Xl = tid & 15;
  const float kv[4] = {1.f, 3.f, 3.f, 1.f};
  float ac[2][2] = {{0.f, 0.f}, {0.f, 0.f}};
#pragma unroll
  for (int c = 0; c < 3; ++c)
#pragma unroll
    for (int d = 0; d < 3; ++d) {
      const float* tp = &Tl[(c * 3 + d) * 324];
      float tv[3][3];
#pragma unroll
      for (int jj = 0; jj < 3; ++jj)
#pragma unroll
        for (int kx = 0; kx < 3; ++kx)
          tv[jj][kx] = tp[(Yl + jj) * 18 + Xl + kx];
#pragma unroll
      for (int py = 0; py < 2; ++py)
#pragma unroll
        for (int px = 0; px < 2; ++px) {
          float s = 0.f;
#pragma unroll
          for (int jj = 0; jj < 3; ++jj) {
            int ay = py + 4 - 2 * jj - c;
            if (ay >= 0 && ay <= 3) {
              float cy = kv[ay];
#pragma unroll
              for (int kx = 0; kx < 3; ++kx) {
                int ax = px + 4 - 2 * kx - d;
                if (ax >= 0 && ax <= 3) s += cy * kv[ax] * tv[jj][kx];
              }
            }
          }
          ac[py][px] += s;
        }
    }
  float dmv = dm[o] * (1.0f / 16.0f);
  int yb = (Ty * 16 + Yl) * 2, xb = (Tx * 16 + Xl) * 2;
  float* op = out + ((size_t)o * 128 + yb) * 128 + xb;
  op[0]   = ac[0][0] * dmv;
  op[1]   = ac[0][1] * dmv;
  op[128] = ac[1][0] * dmv;
  op[129] = ac[1][1] * dmv;
}

extern "C" void kernel_launch(void* const* d_in, const int* in_sizes, int n_in,
                              void* d_out, int out_size, void* d_ws, size_t ws_size,
                              hipStream_t stream) {
  const float* x    = (const float*)d_in[0];
  const float* w    = (const float*)d_in[1];
  const float* aff  = (const float*)d_in[2];
  const float* bias = (const float*)d_in[3];
  const float* cw   = (const float*)d_in[4];
  float* out = (float*)d_out;
  char* ws = (char*)d_ws;
  // ws layout (all 256B aligned): style 16K | S 512K | demod 8K | w9 2.25M | xmt 32M | T 36M  = ~74.2MB
  float* style        = (float*)(ws);
  float* S            = (float*)(ws + 16384);
  float* dmod         = (float*)(ws + 540672);
  unsigned short* w9  = (unsigned short*)(ws + 548864);
  unsigned short* xmt = (unsigned short*)(ws + 2908160);
  float* T            = (float*)(ws + 36462592);

  hipLaunchKernelGGL(style_k, dim3(16), dim3(256), 0, stream, w, aff, bias, style);
  hipLaunchKernelGGL(wprep_k, dim3(512), dim3(256), 0, stream, cw, S, w9);
  hipLaunchKernelGGL(demod_k, dim3(8), dim3(256), 0, stream, style, S, dmod);
  hipLaunchKernelGGL(modx_k, dim3(128, 16, 8), dim3(256), 0, stream, x, style, xmt);
  // per-sample gemm+combine keeps T (37.7MB) L3-resident
  for (int b = 0; b < NB; ++b) {
    hipLaunchKernelGGL(gemm_k, dim3(32, 18, 1), dim3(256), 0, stream,
                       w9, xmt + (size_t)b * SP * INCH, T);
    hipLaunchKernelGGL(combine_k, dim3(16, 256, 1), dim3(256), 0, stream,
                       T, dmod + (size_t)b * OUTCH, out + (size_t)b * OUTCH * 128 * 128);
  }
}

// Round 2
// 439.808 us; speedup vs baseline: 1.3039x; 1.3039x over previous
//
#include <hip/hip_runtime.h>
#include <hip/hip_bf16.h>
#include <math.h>

#define NB 8
#define INCH 512
#define OUTCH 256
#define SP 4096          // 64*64 spatial
#define LAT 512
#define NTAP 9
#define MDIM (NTAP*OUTCH)   // 2304

#define INV_SQRT_LAT 0.044194173824159216f   // 1/sqrt(512)
#define WSCALE 0.014731391274719738f         // 1/sqrt(512*9)

typedef __bf16 bf16x8 __attribute__((ext_vector_type(8)));
typedef float  f32x4  __attribute__((ext_vector_type(4)));

__device__ __forceinline__ unsigned short f2bf(float f) {
  unsigned u = __float_as_uint(f);
  u += 0x7fffu + ((u >> 16) & 1u);       // round-to-nearest-even
  return (unsigned short)(u >> 16);
}
__device__ __forceinline__ float bf2f(unsigned short v) {
  return __uint_as_float((unsigned)v << 16);
}

// ---------------- stage 0a: style[b,i] = w[b,:] @ aff[i,:] / sqrt(512) + bias[i]
__global__ void style_k(const float* __restrict__ w, const float* __restrict__ aff,
                        const float* __restrict__ bias, float* __restrict__ style) {
  int gid = blockIdx.x * 256 + threadIdx.x;       // 4096
  int b = gid >> 9, i = gid & 511;
  const float4* wv = (const float4*)(w + (size_t)b * LAT);
  const float4* av = (const float4*)(aff + (size_t)i * LAT);
  float s = 0.f;
#pragma unroll 4
  for (int l = 0; l < LAT / 4; ++l) {
    float4 a = av[l], ww = wv[l];
    s += a.x * ww.x + a.y * ww.y + a.z * ww.z + a.w * ww.w;
  }
  style[gid] = s * INV_SQRT_LAT + bias[i];
}

// ---------------- stage 0b: S[o,i] = scale^2 * sum_cd base^2 ; w9[tap][o][i] = bf16(scale*base)
__global__ void wprep_k(const float* __restrict__ cw, float* __restrict__ S,
                        unsigned short* __restrict__ w9) {
  int gid = blockIdx.x * 256 + threadIdx.x;       // 131072 = 256*512
  int o = gid >> 9, i = gid & 511;
  const float* p = cw + (size_t)gid * 9;          // gid == o*512+i, layout (o,i,3,3)
  float ss = 0.f, v[9];
#pragma unroll
  for (int t = 0; t < 9; ++t) { v[t] = p[t]; ss += v[t] * v[t]; }
  S[gid] = ss * (WSCALE * WSCALE);
#pragma unroll
  for (int t = 0; t < 9; ++t)
    w9[((size_t)(t * OUTCH + o)) * INCH + i] = f2bf(v[t] * WSCALE);
}

// ---------------- stage 0c: demod[b,o] = rsqrt(sum_i style^2 * S + 1e-8)
__global__ void demod_k(const float* __restrict__ style, const float* __restrict__ S,
                        float* __restrict__ dmod) {
  int gid = blockIdx.x * 256 + threadIdx.x;       // 2048
  int b = gid >> 8, o = gid & 255;
  const float4* sv = (const float4*)(style + (size_t)b * INCH);
  const float4* Sv = (const float4*)(S + (size_t)o * INCH);
  float acc = 0.f;
#pragma unroll 4
  for (int l = 0; l < INCH / 4; ++l) {
    float4 st = sv[l], s2 = Sv[l];
    acc += st.x * st.x * s2.x + st.y * st.y * s2.y + st.z * st.z * s2.z + st.w * st.w * s2.w;
  }
  dmod[gid] = 1.0f / sqrtf(acc + 1e-8f);
}

// ---------------- stage 0d: xmt[b][s][i] = bf16(x[b][i][s] * style[b][i])   (transpose)
__global__ void modx_k(const float* __restrict__ x, const float* __restrict__ style,
                       unsigned short* __restrict__ xmt) {
  __shared__ float tile[32][33];
  int b = blockIdx.z;
  int s0 = blockIdx.x * 32;
  int i0 = blockIdx.y * 32;
  int c = threadIdx.x & 31, r = threadIdx.x >> 5;   // 32 x 8
#pragma unroll
  for (int p = 0; p < 4; ++p) {
    int ii = r + p * 8;
    tile[ii][c] = x[((size_t)(b * INCH + i0 + ii)) * SP + s0 + c] * style[b * INCH + i0 + ii];
  }
  __syncthreads();
#pragma unroll
  for (int p = 0; p < 4; ++p) {
    int ss = r + p * 8;
    xmt[((size_t)(b * SP + s0 + ss)) * INCH + i0 + c] = f2bf(tile[c][ss]);
  }
}

// ---------------- stage 1: T[m, n] = sum_k A[m,k] * B[n,k]   (m97-style bf16 MFMA GEMM, B^T input)
// z-batched over samples. M=2304 N=4096 K=512, tile 128x128, BK=64, T output bf16.
__global__ __launch_bounds__(256, 2)
void gemm_k(const unsigned short* __restrict__ A,   // MDIM x INCH
            const unsigned short* __restrict__ Bm,  // NB x SP x INCH
            unsigned short* __restrict__ C) {       // NB x MDIM x SP (bf16)
  __shared__ __align__(16) unsigned short As[128 * 64];
  __shared__ __align__(16) unsigned short Bs[128 * 64];
  Bm += (size_t)blockIdx.z * SP * INCH;
  C  += (size_t)blockIdx.z * MDIM * SP;
  const int tid  = threadIdx.x;
  const int lane = tid & 63;
  const int wave = tid >> 6;
  const int m0 = blockIdx.y * 128;
  const int n0 = blockIdx.x * 128;
  const int wm = (wave >> 1) * 64;
  const int wn = (wave & 1) * 64;
  const int lrow   = lane >> 3;             // 0..7
  const int gchunk = (lane & 7) ^ lrow;     // swizzled 16B chunk in global row

  f32x4 acc[4][4];
#pragma unroll
  for (int i = 0; i < 4; ++i)
#pragma unroll
    for (int j = 0; j < 4; ++j) acc[i][j] = (f32x4){0.f, 0.f, 0.f, 0.f};

  const int r16  = lane & 15;
  const int quad = lane >> 4;

  for (int k0 = 0; k0 < INCH; k0 += 64) {
#pragma unroll
    for (int it = 0; it < 4; ++it) {
      int rbase = it * 32 + wave * 8;
      const unsigned short* ga = A  + (size_t)(m0 + rbase + lrow) * INCH + k0 + gchunk * 8;
      const unsigned short* gb = Bm + (size_t)(n0 + rbase + lrow) * INCH + k0 + gchunk * 8;
      __builtin_amdgcn_global_load_lds((const __attribute__((address_space(1))) void*)ga,
                                       (__attribute__((address_space(3))) void*)&As[rbase * 64],
                                       16, 0, 0);
      __builtin_amdgcn_global_load_lds((const __attribute__((address_space(1))) void*)gb,
                                       (__attribute__((address_space(3))) void*)&Bs[rbase * 64],
                                       16, 0, 0);
    }
    __syncthreads();
#pragma unroll
    for (int kk = 0; kk < 2; ++kk) {
      bf16x8 af[4], bfr[4];
#pragma unroll
      for (int i = 0; i < 4; ++i) {
        int rowa = wm + i * 16 + r16;
        int cha  = (kk * 4 + quad) ^ (rowa & 7);
        af[i] = *(const bf16x8*)&As[rowa * 64 + cha * 8];
        int rowb = wn + i * 16 + r16;
        int chb  = (kk * 4 + quad) ^ (rowb & 7);
        bfr[i] = *(const bf16x8*)&Bs[rowb * 64 + chb * 8];
      }
#pragma unroll
      for (int i = 0; i < 4; ++i)
#pragma unroll
        for (int j = 0; j < 4; ++j)
          acc[i][j] = __builtin_amdgcn_mfma_f32_16x16x32_bf16(af[i], bfr[j], acc[i][j], 0, 0, 0);
    }
    __syncthreads();
  }
  // epilogue: C/D layout col=lane&15, row=quad*4+reg  [m89-verified]; bf16 store
#pragma unroll
  for (int i = 0; i < 4; ++i)
#pragma unroll
    for (int j = 0; j < 4; ++j)
#pragma unroll
      for (int r = 0; r < 4; ++r) {
        int mrow = m0 + wm + i * 16 + quad * 4 + r;
        int ncol = n0 + wn + j * 16 + r16;
        C[(size_t)mrow * SP + ncol] = f2bf(acc[i][j][r]);
      }
}

// ---------------- stage 2: separable parity-combine + 4x4 blur + demod
// x-pass: V[c][yr][xp] = sum_{d,kx} kv[(xp&1)+4-2kx-d] * T[c*3+d][yr][X+kx]
// y-pass: out[2Y+py][xp] = dm/16 * sum_{c,jj} kv[py+4-2jj-c] * V[c][Y+jj][xp]
#define TLS 342   // 18*19 (padded row stride 19)
#define VS  648   // 18*36 (padded row stride 36, keeps 16B alignment)
__global__ void combine_k(const unsigned short* __restrict__ T, const float* __restrict__ dm,
                          float* __restrict__ out) {
  __shared__ __align__(16) float Tl[9 * TLS];
  __shared__ __align__(16) float V[3 * VS];
  T   += (size_t)blockIdx.z * MDIM * SP;
  dm  += (size_t)blockIdx.z * OUTCH;
  out += (size_t)blockIdx.z * OUTCH * 128 * 128;
  const int o = blockIdx.y;
  const int Ty = blockIdx.x >> 2, Tx = blockIdx.x & 3;
  const int tid = threadIdx.x;
  // load 9 taps of 18x18 halo tile (bf16 -> fp32 in LDS)
  for (int idx = tid; idx < 9 * 324; idx += 256) {
    int tap = idx / 324;
    int rem = idx - tap * 324;
    int yy = rem / 18;
    int xx = rem - yy * 18;
    int Yg = Ty * 16 - 1 + yy;
    int Xg = Tx * 16 - 1 + xx;
    float v = 0.f;
    if ((unsigned)Yg < 64u && (unsigned)Xg < 64u)
      v = bf2f(T[((size_t)(tap * OUTCH + o)) * SP + Yg * 64 + Xg]);
    Tl[tap * TLS + yy * 19 + xx] = v;
  }
  __syncthreads();
  // x-pass: 54 rows (c,yr) x 4 thread-groups of 8 xp each
  {
    int r = tid >> 2;
    if (r < 54) {
      int c = r / 18;
      int yr = r - c * 18;
      int X0 = (tid & 3) * 4;
      const float* base = &Tl[c * 3 * TLS + yr * 19 + X0];
      float t0[6], t1[6], t2[6];
#pragma unroll
      for (int k = 0; k < 6; ++k) {
        t0[k] = base[k];
        t1[k] = base[TLS + k];
        t2[k] = base[2 * TLS + k];
      }
      float* vrow = &V[c * VS + yr * 36 + X0 * 2];
#pragma unroll
      for (int Xl = 0; Xl < 4; ++Xl) {
        vrow[2 * Xl]     = t1[Xl] + 3.f * t2[Xl] + 3.f * t0[Xl + 1] + 3.f * t1[Xl + 1] + t2[Xl + 1] + t0[Xl + 2];
        vrow[2 * Xl + 1] = t2[Xl] + t0[Xl + 1] + 3.f * t1[Xl + 1] + 3.f * t2[Xl + 1] + 3.f * t0[Xl + 2] + t1[Xl + 2];
      }
    }
  }
  __syncthreads();
  // y-pass: 32 out rows x 8 xp-groups of 4
  const int y  = tid >> 3;        // 0..31
  const int py = y & 1;
  const int Yl = y >> 1;
  const int xp0 = (tid & 7) * 4;
  f32x4 vv[3][3];
#pragma unroll
  for (int c = 0; c < 3; ++c)
#pragma unroll
    for (int jj = 0; jj < 3; ++jj)
      vv[c][jj] = *(const f32x4*)&V[c * VS + (Yl + jj) * 36 + xp0];
  f32x4 o4;
  if (py == 0)
    o4 = vv[1][0] + 3.f * vv[2][0] + 3.f * vv[0][1] + 3.f * vv[1][1] + vv[2][1] + vv[0][2];
  else
    o4 = vv[2][0] + vv[0][1] + 3.f * vv[1][1] + 3.f * vv[2][1] + 3.f * vv[0][2] + vv[1][2];
  float dmv = dm[o] * (1.0f / 16.0f);
  o4 *= dmv;
  *(f32x4*)&out[((size_t)o * 128 + Ty * 32 + y) * 128 + Tx * 32 + xp0] = o4;
}

extern "C" void kernel_launch(void* const* d_in, const int* in_sizes, int n_in,
                              void* d_out, int out_size, void* d_ws, size_t ws_size,
                              hipStream_t stream) {
  const float* x    = (const float*)d_in[0];
  const float* w    = (const float*)d_in[1];
  const float* aff  = (const float*)d_in[2];
  const float* bias = (const float*)d_in[3];
  const float* cw   = (const float*)d_in[4];
  float* out = (float*)d_out;
  char* ws = (char*)d_ws;
  // ws layout: style 16K | S 512K | demod 8K | w9 2.25M | xmt 32M | T(bf16) 151M  = ~187.5MB
  float* style        = (float*)(ws);
  float* S            = (float*)(ws + 16384);
  float* dmod         = (float*)(ws + 540672);
  unsigned short* w9  = (unsigned short*)(ws + 548864);
  unsigned short* xmt = (unsigned short*)(ws + 2908160);
  unsigned short* T   = (unsigned short*)(ws + 36462592);

  hipLaunchKernelGGL(style_k, dim3(16), dim3(256), 0, stream, w, aff, bias, style);
  hipLaunchKernelGGL(wprep_k, dim3(512), dim3(256), 0, stream, cw, S, w9);
  hipLaunchKernelGGL(demod_k, dim3(8), dim3(256), 0, stream, style, S, dmod);
  hipLaunchKernelGGL(modx_k, dim3(128, 16, 8), dim3(256), 0, stream, x, style, xmt);
  // batched: T bf16 (151MB) stays L3-resident across both dispatches
  hipLaunchKernelGGL(gemm_k, dim3(32, 18, NB), dim3(256), 0, stream, w9, xmt, T);
  hipLaunchKernelGGL(combine_k, dim3(16, 256, NB), dim3(256), 0, stream, T, dmod, out);
}